// Round 2
// baseline (2196.763 us; speedup 1.0000x reference)
//
#include <hip/hip_runtime.h>

#define NHEADS 8
#define DIM 384
#define BB 4
#define HW 16384      // 128*128
#define CPH 48        // channels per head

// ---------------- GEMM: Y[b][o][n] = sum_c W[o][c] * X[b][c][n] ----------------
// W is pre-offset by caller; Cout is the output-buffer channel stride.
#define GT_O 128
#define GT_N 128
#define GT_K 8

__global__ __launch_bounds__(256) void gemm_wx(
    const float* __restrict__ W, const float* __restrict__ X,
    float* __restrict__ Y, int Cout, int Cin)
{
    const int N = HW;
    const int n0 = blockIdx.x * GT_N;
    const int o0 = blockIdx.y * GT_O;
    const int b  = blockIdx.z;
    const float* Xb = X + (size_t)b * Cin * N;
    float* Yb = Y + (size_t)b * Cout * N;

    __shared__ float sW[GT_K][GT_O];
    __shared__ float sX[GT_K][GT_N];

    const int t  = threadIdx.x;
    const int tx = t & 15, ty = t >> 4;
    const int of = ty * 8, nf = tx * 8;

    const int xkc = t >> 5, xj = (t & 31) << 2;   // X stage: 8 rows x 128 cols
    const int wo  = t >> 1, wc = (t & 1) << 2;    // W stage: 128 o x 8 c

    float acc[8][8];
    #pragma unroll
    for (int i = 0; i < 8; ++i)
        #pragma unroll
        for (int j = 0; j < 8; ++j) acc[i][j] = 0.f;

    for (int c0 = 0; c0 < Cin; c0 += GT_K) {
        const float4 xv = *(const float4*)&Xb[(size_t)(c0 + xkc) * N + n0 + xj];
        const float4 wv = *(const float4*)&W[(size_t)(o0 + wo) * Cin + c0 + wc];
        __syncthreads();
        *(float4*)&sX[xkc][xj] = xv;
        sW[wc + 0][wo] = wv.x;
        sW[wc + 1][wo] = wv.y;
        sW[wc + 2][wo] = wv.z;
        sW[wc + 3][wo] = wv.w;
        __syncthreads();
        #pragma unroll
        for (int kc = 0; kc < GT_K; ++kc) {
            float a[8], bv[8];
            *(float4*)&a[0]  = *(const float4*)&sW[kc][of];
            *(float4*)&a[4]  = *(const float4*)&sW[kc][of + 4];
            *(float4*)&bv[0] = *(const float4*)&sX[kc][nf];
            *(float4*)&bv[4] = *(const float4*)&sX[kc][nf + 4];
            #pragma unroll
            for (int i = 0; i < 8; ++i)
                #pragma unroll
                for (int j = 0; j < 8; ++j)
                    acc[i][j] = fmaf(a[i], bv[j], acc[i][j]);
        }
    }

    #pragma unroll
    for (int i = 0; i < 8; ++i) {
        float* dst = &Yb[(size_t)(o0 + of + i) * N + n0 + nf];
        *(float4*)dst       = make_float4(acc[i][0], acc[i][1], acc[i][2], acc[i][3]);
        *(float4*)(dst + 4) = make_float4(acc[i][4], acc[i][5], acc[i][6], acc[i][7]);
    }
}

// ------------- depthwise 3x3 SAME (cross-correlation) + optional sumsq -------------
// in: [B][128][HW] staging chunk. w9: pre-offset to chunk start.
// out: [B][384][HW] group buffer, channels [out_off, out_off+128).
// ss (nullable): [B][768], written at ss_off + local_ch.
__global__ __launch_bounds__(256) void dwconv_ss(
    const float* __restrict__ in, const float* __restrict__ w9,
    float* __restrict__ out, int out_off,
    float* __restrict__ ss, int ss_off)
{
    const int p  = blockIdx.x;             // b*128 + cl
    const int cl = p & 127;
    const int b  = p >> 7;
    const float* ip = in + (size_t)p * HW;
    float* op = out + ((size_t)b * DIM + out_off + cl) * HW;
    float w[9];
    #pragma unroll
    for (int i = 0; i < 9; ++i) w[i] = w9[cl * 9 + i];

    float ssum = 0.f;
    for (int idx = threadIdx.x; idx < HW; idx += 256) {
        const int y = idx >> 7, x = idx & 127;
        float a = 0.f;
        #pragma unroll
        for (int ky = 0; ky < 3; ++ky) {
            const int yy = y + ky - 1;
            if ((unsigned)yy < 128u) {
                #pragma unroll
                for (int kx = 0; kx < 3; ++kx) {
                    const int xx = x + kx - 1;
                    if ((unsigned)xx < 128u)
                        a = fmaf(ip[yy * 128 + xx], w[ky * 3 + kx], a);
                }
            }
        }
        op[idx] = a;
        ssum = fmaf(a, a, ssum);
    }

    if (ss != nullptr) {
        __shared__ float red[256];
        red[threadIdx.x] = ssum;
        __syncthreads();
        for (int s = 128; s > 0; s >>= 1) {
            if (threadIdx.x < s) red[threadIdx.x] += red[threadIdx.x + s];
            __syncthreads();
        }
        if (threadIdx.x == 0) ss[b * (2 * DIM) + ss_off + cl] = red[0];
    }
}

// ------------- raw gram G[b,h,c,d] = sum_n q[c,n] * k[d,n] (atomic partials) -------------
// qA, kA: [B][384][HW] group buffers (post-dwconv q~ and k~).
#define GCH 512
__global__ __launch_bounds__(256) void gram_qk(
    const float* __restrict__ qA, const float* __restrict__ kA,
    float* __restrict__ G)
{
    const int n0 = blockIdx.x * GCH;
    const int h  = blockIdx.y;
    const int b  = blockIdx.z;
    const float* qb = qA + ((size_t)b * DIM + h * CPH) * HW;
    const float* kb = kA + ((size_t)b * DIM + h * CPH) * HW;

    __shared__ float qs[CPH][132];
    __shared__ float ks[CPH][132];

    const int t  = threadIdx.x;
    const int tx = t & 15, ty = t >> 4;
    float acc[3][3] = {{0.f,0.f,0.f},{0.f,0.f,0.f},{0.f,0.f,0.f}};

    for (int sc = 0; sc < GCH; sc += 128) {
        __syncthreads();
        #pragma unroll
        for (int i = 0; i < 6; ++i) {
            const int idx = t + i * 256;          // 0..1535
            const int row = idx >> 5, col = (idx & 31) << 2;
            const size_t g = (size_t)row * HW + n0 + sc + col;
            const float4 qv = *(const float4*)&qb[g];
            const float4 kv = *(const float4*)&kb[g];
            *(float4*)&qs[row][col] = qv;
            *(float4*)&ks[row][col] = kv;
        }
        __syncthreads();
        for (int j = 0; j < 128; j += 4) {
            float qv[3][4], kv[3][4];
            #pragma unroll
            for (int i = 0; i < 3; ++i) {
                const float4 tq = *(const float4*)&qs[ty * 3 + i][j];
                qv[i][0] = tq.x; qv[i][1] = tq.y; qv[i][2] = tq.z; qv[i][3] = tq.w;
                const float4 tk = *(const float4*)&ks[tx * 3 + i][j];
                kv[i][0] = tk.x; kv[i][1] = tk.y; kv[i][2] = tk.z; kv[i][3] = tk.w;
            }
            #pragma unroll
            for (int i = 0; i < 3; ++i)
                #pragma unroll
                for (int jj = 0; jj < 3; ++jj)
                    acc[i][jj] += qv[i][0]*kv[jj][0] + qv[i][1]*kv[jj][1]
                                + qv[i][2]*kv[jj][2] + qv[i][3]*kv[jj][3];
        }
    }

    float* Gp = G + ((size_t)(b * NHEADS + h)) * CPH * CPH;
    #pragma unroll
    for (int i = 0; i < 3; ++i)
        #pragma unroll
        for (int j = 0; j < 3; ++j)
            atomicAdd(&Gp[(ty * 3 + i) * CPH + tx * 3 + j], acc[i][j]);
}

// ------------- normalize + 4x top-k softmax, combined into one P -------------
__global__ void topk_combine(
    const float* __restrict__ G, const float* __restrict__ ss,
    const float* __restrict__ temp,
    const float* __restrict__ a1, const float* __restrict__ a2,
    const float* __restrict__ a3, const float* __restrict__ a4,
    float* __restrict__ P)
{
    const int bh = blockIdx.x;
    const int b = bh >> 3, h = bh & 7;
    const int r = threadIdx.x;
    if (r >= CPH) return;
    const float tpr = temp[h];
    const float* ssb = ss + b * (2 * DIM);
    const float invq = 1.f / sqrtf(ssb[h * CPH + r]);
    const float* Grow = G + ((size_t)bh * CPH + r) * CPH;

    float att[CPH];
    for (int d = 0; d < CPH; ++d)
        att[d] = Grow[d] * invq * (1.f / sqrtf(ssb[DIM + h * CPH + d])) * tpr;

    // sort descending (48 elems, per-thread row)
    float s[CPH];
    for (int i = 0; i < CPH; ++i) s[i] = att[i];
    for (int i = 1; i < CPH; ++i) {
        const float key = s[i];
        int j = i - 1;
        while (j >= 0 && s[j] < key) { s[j + 1] = s[j]; --j; }
        s[j + 1] = key;
    }
    // k = C/2, 2C/3, 3C/4, 4C/5 = 24, 32, 36, 38
    const float thr0 = s[23], thr1 = s[31], thr2 = s[35], thr3 = s[37];
    const float mx = s[0];

    float e[CPH];
    float Z0 = 0.f, Z1 = 0.f, Z2 = 0.f, Z3 = 0.f;
    for (int d = 0; d < CPH; ++d) {
        const float ev = expf(att[d] - mx);
        e[d] = ev;
        if (att[d] >= thr0) Z0 += ev;
        if (att[d] >= thr1) Z1 += ev;
        if (att[d] >= thr2) Z2 += ev;
        if (att[d] >= thr3) Z3 += ev;
    }
    const float w0 = a1[0] / Z0, w1 = a2[0] / Z1, w2 = a3[0] / Z2, w3 = a4[0] / Z3;
    float* Prow = P + ((size_t)bh * CPH + r) * CPH;
    for (int d = 0; d < CPH; ++d) {
        float pv = 0.f;
        if (att[d] >= thr0) pv += w0 * e[d];
        if (att[d] >= thr1) pv += w1 * e[d];
        if (att[d] >= thr2) pv += w2 * e[d];
        if (att[d] >= thr3) pv += w3 * e[d];
        Prow[d] = pv;
    }
}

// ------------- out1[b, h*48+c, n] = sum_d P[b,h,c,d] * v[b,h,d,n] -------------
// v: [B][384][HW] group buffer; out1: [B][384][HW] group buffer.
__global__ __launch_bounds__(256) void pv_apply(
    const float* __restrict__ v, const float* __restrict__ P,
    float* __restrict__ out1)
{
    const int bh = blockIdx.y;
    const int b = bh >> 3, h = bh & 7;
    const int n0 = blockIdx.x * 256;

    __shared__ float sPT[CPH][52];   // [d][c], padded
    const int t = threadIdx.x;
    for (int i = t; i < CPH * CPH; i += 256) {
        const int c = i / CPH, d = i % CPH;
        sPT[d][c] = P[(size_t)bh * CPH * CPH + i];
    }
    __syncthreads();

    const int cg = t >> 6;        // wave id: 0..3 -> c-group of 12
    const int lane = t & 63;
    const float* vb = v + ((size_t)b * DIM + h * CPH) * HW + n0 + lane * 4;

    float acc[12][4];
    #pragma unroll
    for (int i = 0; i < 12; ++i)
        #pragma unroll
        for (int j = 0; j < 4; ++j) acc[i][j] = 0.f;

    for (int d = 0; d < CPH; ++d) {
        const float4 vv = *(const float4*)&vb[(size_t)d * HW];
        const float vvs[4] = {vv.x, vv.y, vv.z, vv.w};
        #pragma unroll
        for (int cq = 0; cq < 3; ++cq) {
            const float4 pc = *(const float4*)&sPT[d][cg * 12 + cq * 4];
            const float pcs[4] = {pc.x, pc.y, pc.z, pc.w};
            #pragma unroll
            for (int a = 0; a < 4; ++a)
                #pragma unroll
                for (int jn = 0; jn < 4; ++jn)
                    acc[cq * 4 + a][jn] = fmaf(pcs[a], vvs[jn], acc[cq * 4 + a][jn]);
        }
    }

    float* ob = out1 + ((size_t)b * DIM + h * CPH + cg * 12) * HW + n0 + lane * 4;
    #pragma unroll
    for (int ci = 0; ci < 12; ++ci)
        *(float4*)&ob[(size_t)ci * HW] =
            make_float4(acc[ci][0], acc[ci][1], acc[ci][2], acc[ci][3]);
}

extern "C" void kernel_launch(void* const* d_in, const int* in_sizes, int n_in,
                              void* d_out, int out_size, void* d_ws, size_t ws_size,
                              hipStream_t stream)
{
    const float* x      = (const float*)d_in[0];
    const float* qkv_w  = (const float*)d_in[1];
    const float* dw_w   = (const float*)d_in[2];
    const float* proj_w = (const float*)d_in[3];
    const float* temp   = (const float*)d_in[4];
    const float* a1 = (const float*)d_in[5];
    const float* a2 = (const float*)d_in[6];
    const float* a3 = (const float*)d_in[7];
    const float* a4 = (const float*)d_in[8];
    float* out = (float*)d_out;

    // ---- workspace layout (floats) ----
    const size_t grp  = (size_t)BB * DIM * HW;   // 25,165,824 (100.66 MB)
    const size_t stg  = (size_t)BB * 128 * HW;   //  8,388,608 (33.55 MB)
    const size_t need = (2 * grp + stg + (size_t)BB * 2 * DIM
                         + 2 * (size_t)BB * NHEADS * CPH * CPH) * sizeof(float);
    if (ws_size < need) return;   // graceful bail instead of OOB crash

    float* ws     = (float*)d_ws;
    float* bufA   = ws;                 // q~  -> later out1
    float* bufB   = bufA + grp;         // k~  -> later v~
    float* stag   = bufB + grp;         // raw qkv 128-ch chunk
    float* buf_ss = stag + stg;         // [B][768] sumsq q,k
    float* buf_G  = buf_ss + (size_t)BB * 2 * DIM;            // [B][8][48][48]
    float* buf_P  = buf_G + (size_t)BB * NHEADS * CPH * CPH;  // combined weights

    hipMemsetAsync(buf_G, 0, (size_t)BB * NHEADS * CPH * CPH * sizeof(float), stream);

    const dim3 ggrid(HW / GT_N, 1, BB);
    const dim3 dgrid(BB * 128);

    // q group -> bufA  (channels 0..383, ss offsets 0..383)
    for (int g = 0; g < 3; ++g) {
        gemm_wx<<<ggrid, 256, 0, stream>>>(qkv_w + (size_t)(g * 128) * DIM, x, stag, 128, DIM);
        dwconv_ss<<<dgrid, 256, 0, stream>>>(stag, dw_w + (size_t)(g * 128) * 9,
                                             bufA, g * 128, buf_ss, g * 128);
    }
    // k group -> bufB  (ss offsets 384..767)
    for (int g = 0; g < 3; ++g) {
        gemm_wx<<<ggrid, 256, 0, stream>>>(qkv_w + (size_t)(DIM + g * 128) * DIM, x, stag, 128, DIM);
        dwconv_ss<<<dgrid, 256, 0, stream>>>(stag, dw_w + (size_t)(DIM + g * 128) * 9,
                                             bufB, g * 128, buf_ss, DIM + g * 128);
    }

    gram_qk<<<dim3(HW / GCH, NHEADS, BB), 256, 0, stream>>>(bufA, bufB, buf_G);
    topk_combine<<<dim3(BB * NHEADS), 64, 0, stream>>>(
        buf_G, buf_ss, temp, a1, a2, a3, a4, buf_P);

    // v group -> bufB (k~ is dead after gram)
    for (int g = 0; g < 3; ++g) {
        gemm_wx<<<ggrid, 256, 0, stream>>>(qkv_w + (size_t)(2 * DIM + g * 128) * DIM, x, stag, 128, DIM);
        dwconv_ss<<<dgrid, 256, 0, stream>>>(stag, dw_w + (size_t)(2 * DIM + g * 128) * 9,
                                             bufB, g * 128, nullptr, 0);
    }

    // out1 -> bufA (q~ is dead after gram)
    pv_apply<<<dim3(HW / 256, BB * NHEADS), 256, 0, stream>>>(bufB, buf_P, bufA);

    // proj: out = proj_w @ out1
    gemm_wx<<<dim3(HW / GT_N, DIM / GT_O, BB), 256, 0, stream>>>(proj_w, bufA, out, DIM, DIM);
}